// Round 20
// baseline (213.508 us; speedup 1.0000x reference)
//
#include <hip/hip_runtime.h>
#include <hip/hip_fp16.h>

#define MU 256
#define NPIX (MU*MU)
#define ML 3
#define KS 7
#define LCH 7
#define NENT 35   // 28 upper-tri M entries + 7 b entries
#define RBLK 64   // partial blocks per sample in reduce stage-1

typedef _Float16 half2r __attribute__((ext_vector_type(2)));

__device__ __forceinline__ float dot2f(half2r a, half2r b, float c) {
#if __has_builtin(__builtin_amdgcn_fdot2)
    return __builtin_amdgcn_fdot2(a, b, c, false);
#else
    return c + (float)a.x*(float)b.x + (float)a.y*(float)b.y;
#endif
}

// load 4 consecutive halfs (8B) -> float4
__device__ __forceinline__ float4 load_h4(const __half* p) {
    __half2 a = *(const __half2*)p;
    __half2 b = *(const __half2*)(p + 2);
    float2 fa = __half22float2(a), fb = __half22float2(b);
    return make_float4(fa.x, fa.y, fb.x, fb.y);
}

// ---------------- MLP: per-sample dynamic kernels ----------------
// Packs w2 into the 8 half2 alignments needed by the dot2 conv:
//   group g = (c*7+i)*3+co (0..62), entries p=0..7:
//   p<4  (even set, accA): (0,w0),(w1,w2),(w3,w4),(w5,w6)
//   p>=4 (odd  set, accB): (w0,w1),(w2,w3),(w4,w5),(w6,0)
__global__ void mlp_kernel(const float* __restrict__ kernelA,
                           const float* __restrict__ fc1_w1, const float* __restrict__ fc1_b1,
                           const float* __restrict__ fc1_w2, const float* __restrict__ fc1_b2,
                           const float* __restrict__ fc2_w1, const float* __restrict__ fc2_b1,
                           const float* __restrict__ fc2_w2, const float* __restrict__ fc2_b2,
                           float* __restrict__ w1_out, half2r* __restrict__ w2p) {
    int b = blockIdx.x;
    int t = threadIdx.x;
    __shared__ float kA[9];
    __shared__ float h1[200], h2[200];
    __shared__ float w2s[441];
    if (t < 9) kA[t] = kernelA[b*9 + t];
    __syncthreads();
    if (t < 200) {
        float s1 = fc1_b1[t], s2 = fc2_b1[t];
        #pragma unroll
        for (int i = 0; i < 9; ++i) {
            s1 += kA[i] * fc1_w1[i*200 + t];
            s2 += kA[i] * fc2_w1[i*200 + t];
        }
        h1[t] = fmaxf(s1, 0.f);
        h2[t] = fmaxf(s2, 0.f);
    }
    __syncthreads();
    if (t < 147) {
        float s = fc1_b2[t];
        for (int i = 0; i < 200; ++i) s += h1[i] * fc1_w2[i*147 + t];
        w1_out[b*147 + t] = s;
    }
    for (int o = t; o < 441; o += 256) {
        float s = fc2_b2[o];
        for (int i = 0; i < 200; ++i) s += h2[i] * fc2_w2[i*441 + o];
        w2s[o] = s;
    }
    __syncthreads();
    for (int u = t; u < 504; u += 256) {
        int grp = u / 8, p = u % 8;
        int co = grp % 3, i = (grp / 3) % 7, c = grp / 21;
        const float* w = &w2s[co*147 + c*49 + i*7];   // w[j], j=0..6
        float lo, hi;
        if (p < 4) { lo = (p == 0) ? 0.f : w[2*p - 1]; hi = w[2*p]; }
        else       { int q = p - 4; lo = w[2*q]; hi = (q == 3) ? 0.f : w[2*q + 1]; }
        half2r hp; hp.x = (_Float16)lo; hp.y = (_Float16)hi;
        w2p[(size_t)b*504 + u] = hp;
    }
}

// ---- FUSED: r = f - conv3x3(x) into LDS (fp32), interior r written as
//      fp16, then conv7x7 1->3ch from LDS; G1 written as fp16. ----
__global__ __launch_bounds__(256) void res_g1_kernel(
        const float* __restrict__ x, const float* __restrict__ f,
        const float* __restrict__ kA, const float* __restrict__ w1,
        __half* __restrict__ r, __half* __restrict__ G1) {
    int b = blockIdx.z;
    __shared__ float xt[24][144];
    __shared__ float rt[22][136];
    int tx = threadIdx.x;
    int ty = threadIdx.y;
    int tid = ty*64 + tx;
    int x0 = blockIdx.x*128, y0 = blockIdx.y*16;
    const float* xb = x + (size_t)b*NPIX;
    const float* fb = f + (size_t)b*NPIX;
    const float* wgt = w1 + (size_t)b*147;
    float k[9];
    #pragma unroll
    for (int i = 0; i < 9; ++i) k[i] = kA[b*9 + i];

    for (int u = tid; u < 24*36; u += 256) {
        int row = u / 36, q4 = u % 36;
        int yy = y0 + row - 4;
        int xx = x0 - 8 + q4*4;
        float4 vv = make_float4(0.f, 0.f, 0.f, 0.f);
        if (yy >= 0 && yy < MU && xx >= 0 && xx < MU)
            vv = *(const float4*)(xb + yy*MU + xx);
        *(float4*)&xt[row][q4*4] = vv;
    }
    __syncthreads();

    for (int u = tid; u < 22*34; u += 256) {
        int row = u / 34, c4 = u % 34;
        int Y = y0 - 3 + row;
        int X = x0 - 4 + 4*c4;
        bool inb = (Y >= 0 && Y < MU && X >= 0 && X < MU);
        float4 fv = make_float4(0.f, 0.f, 0.f, 0.f);
        if (inb) fv = *(const float4*)(fb + Y*MU + X);
        float fr[4] = {fv.x, fv.y, fv.z, fv.w};
        float rr[4];
        #pragma unroll
        for (int cc = 0; cc < 4; ++cc) {
            float s = 0.f;
            #pragma unroll
            for (int di = 0; di < 3; ++di)
                #pragma unroll
                for (int dj = 0; dj < 3; ++dj)
                    s += xt[row + di][4*c4 + 3 + cc + dj] * k[di*3 + dj];
            rr[cc] = inb ? (fr[cc] - s) : 0.f;
        }
        *(float4*)&rt[row][4*c4] = make_float4(rr[0], rr[1], rr[2], rr[3]);
    }
    __syncthreads();

    float accA[3][4], accB[3][4];
    #pragma unroll
    for (int co = 0; co < 3; ++co)
        #pragma unroll
        for (int dy = 0; dy < 4; ++dy) { accA[co][dy] = 0.f; accB[co][dy] = 0.f; }

    int ry = ty*4;
    #pragma unroll
    for (int ir = 0; ir < 10; ++ir) {
        float v[10];
        #pragma unroll
        for (int h = 0; h < 5; ++h)
            *(float2*)&v[h*2] = *(float2*)&rt[ry + ir][2*tx + h*2];
        #pragma unroll
        for (int dy = 0; dy < 4; ++dy) {
            int i = ir - dy;
            if (i >= 0 && i <= 6) {
                #pragma unroll
                for (int co = 0; co < 3; ++co)
                    #pragma unroll
                    for (int j = 0; j < 7; ++j) {
                        float w = wgt[(co*7 + i)*7 + j];
                        accA[co][dy] += v[1 + j] * w;
                        accB[co][dy] += v[2 + j] * w;
                    }
            }
        }
    }
    #pragma unroll
    for (int dy = 0; dy < 4; ++dy) {
        size_t pr = (size_t)b*NPIX + (size_t)(y0 + ry + dy)*MU + x0 + 2*tx;
        float2 rv2 = *(float2*)&rt[3 + ry + dy][4 + 2*tx];
        *(__half2*)&r[pr] = __float22half2_rn(rv2);
        size_t p = (size_t)b*3*NPIX + (size_t)(y0 + ry + dy)*MU + x0 + 2*tx;
        #pragma unroll
        for (int co = 0; co < 3; ++co)
            *(__half2*)&G1[p + (size_t)co*NPIX] =
                __float22half2_rn(make_float2(accA[co][dy], accB[co][dy]));
    }
}

// ---- conv7x7 3->3ch via v_dot2_f32_f16: fp16 LDS tile (11.4 KB),
//      fp32 accumulators. ----
__global__ __launch_bounds__(256) void conv7_g2(
        const __half* __restrict__ G1, const half2r* __restrict__ w2p,
        __half* __restrict__ G2) {
    int b = blockIdx.z;
    __shared__ _Float16 tile[3][14][136];
    int tx = threadIdx.x;
    int ty = threadIdx.y;
    int tid = ty*64 + tx;
    int x0 = blockIdx.x*128, y0 = blockIdx.y*8;
    const __half* g1b = G1 + (size_t)b*3*NPIX;
    const half2r* wp = w2p + (size_t)b*504;

    for (int u = tid; u < 3*14*34; u += 256) {
        int c = u / (14*34);
        int rem = u % (14*34);
        int row = rem / 34, q4 = rem % 34;
        int yy = y0 + row - 3;
        int xx = x0 - 4 + q4*4;
        ushort4 vv = make_ushort4(0, 0, 0, 0);
        if (yy >= 0 && yy < MU && xx >= 0 && xx < MU)
            vv = *(const ushort4*)(g1b + (size_t)c*NPIX + yy*MU + xx);
        *(ushort4*)&tile[c][row][q4*4] = vv;
    }
    __syncthreads();

    float accA[3][2], accB[3][2];
    #pragma unroll
    for (int co = 0; co < 3; ++co)
        #pragma unroll
        for (int dy = 0; dy < 2; ++dy) { accA[co][dy] = 0.f; accB[co][dy] = 0.f; }

    int ry = ty*2;
    #pragma unroll
    for (int c = 0; c < 3; ++c) {
        #pragma unroll
        for (int ir = 0; ir < 8; ++ir) {
            half2r P[5];
            #pragma unroll
            for (int q = 0; q < 5; ++q)
                P[q] = *(const half2r*)&tile[c][ry + ir][2*tx + 2*q];
            #pragma unroll
            for (int dy = 0; dy < 2; ++dy) {
                int i = ir - dy;
                if (i >= 0 && i <= 6) {
                    #pragma unroll
                    for (int co = 0; co < 3; ++co) {
                        const half2r* wv = wp + ((c*7 + i)*3 + co)*8;
                        accA[co][dy] = dot2f(P[0], wv[0], accA[co][dy]);
                        accA[co][dy] = dot2f(P[1], wv[1], accA[co][dy]);
                        accA[co][dy] = dot2f(P[2], wv[2], accA[co][dy]);
                        accA[co][dy] = dot2f(P[3], wv[3], accA[co][dy]);
                        accB[co][dy] = dot2f(P[1], wv[4], accB[co][dy]);
                        accB[co][dy] = dot2f(P[2], wv[5], accB[co][dy]);
                        accB[co][dy] = dot2f(P[3], wv[6], accB[co][dy]);
                        accB[co][dy] = dot2f(P[4], wv[7], accB[co][dy]);
                    }
                }
            }
        }
    }
    #pragma unroll
    for (int dy = 0; dy < 2; ++dy) {
        size_t p = (size_t)b*3*NPIX + (size_t)(y0 + ry + dy)*MU + x0 + 2*tx;
        #pragma unroll
        for (int co = 0; co < 3; ++co)
            *(__half2*)&G2[p + (size_t)co*NPIX] =
                __float22half2_rn(make_float2(accA[co][dy], accB[co][dy]));
    }
}

// ---- S = depthwise3x3(G, kernelA); stage-1 Gram partials.
//      fp16 LDS tile (18.4 KB -> 8 blocks/CU), fp32 compute,
//      butterfly split-reduction. ----
__global__ __launch_bounds__(256, 4) void reduce_kernel(
        const __half* __restrict__ r, const __half* __restrict__ G1,
        const __half* __restrict__ G2, const float* __restrict__ kA,
        float* __restrict__ partial) {
    int b = blockIdx.z;
    __shared__ _Float16 tile[7][18][72];
    __shared__ float wsum[NENT][4];
    int tx = threadIdx.x;
    int ty = threadIdx.y;
    int tid = ty*64 + tx;
    float k[9];
    #pragma unroll
    for (int i = 0; i < 9; ++i) k[i] = kA[b*9 + i];

    const __half* srcs[7] = {
        r  + (size_t)b*NPIX,
        G1 + (size_t)b*3*NPIX, G1 + (size_t)b*3*NPIX + NPIX, G1 + (size_t)b*3*NPIX + 2*NPIX,
        G2 + (size_t)b*3*NPIX, G2 + (size_t)b*3*NPIX + NPIX, G2 + (size_t)b*3*NPIX + 2*NPIX
    };

    int x0 = blockIdx.x*64;
    int ysub = blockIdx.y*16;

    #pragma unroll
    for (int c = 0; c < 7; ++c) {
        const __half* src = srcs[c];
        for (int u = tid; u < 18*18; u += 256) {
            int row = u / 18, q4 = u % 18;
            int yy = ysub + row - 1;
            int xx = x0 - 4 + q4*4;
            ushort4 vv = make_ushort4(0, 0, 0, 0);
            if (yy >= 0 && yy < MU && xx >= 0 && xx < MU)
                vv = *(const ushort4*)(src + yy*MU + xx);
            *(ushort4*)&tile[c][row][q4*4] = vv;
        }
    }
    __syncthreads();

    float acc[64];
    #pragma unroll
    for (int e = 0; e < 64; ++e) acc[e] = 0.f;

    int ry = ty*4;
    float S_all[7][4];
    #pragma unroll
    for (int c = 0; c < 7; ++c) {
        float S0 = 0.f, S1 = 0.f, S2 = 0.f, S3 = 0.f;
        #pragma unroll
        for (int t = 0; t < 6; ++t) {
            float v0 = (float)tile[c][ry + t][tx + 3];
            float v1 = (float)tile[c][ry + t][tx + 4];
            float v2 = (float)tile[c][ry + t][tx + 5];
            float e0 = v0*k[0] + v1*k[1] + v2*k[2];
            float e1 = v0*k[3] + v1*k[4] + v2*k[5];
            float e2 = v0*k[6] + v1*k[7] + v2*k[8];
            if (t == 0) { S0 += e0; }
            if (t == 1) { S1 += e0; S0 += e1; }
            if (t == 2) { S2 += e0; S1 += e1; S0 += e2; }
            if (t == 3) { S3 += e0; S2 += e1; S1 += e2; }
            if (t == 4) {           S3 += e1; S2 += e2; }
            if (t == 5) {                     S3 += e2; }
        }
        S_all[c][0] = S0; S_all[c][1] = S1; S_all[c][2] = S2; S_all[c][3] = S3;
    }
    #pragma unroll
    for (int dy = 0; dy < 4; ++dy) {
        float rv = (float)tile[0][ry + dy + 1][tx + 4];
        int idx = 0;
        #pragma unroll
        for (int l = 0; l < 7; ++l) {
            #pragma unroll
            for (int m = l; m < 7; ++m) {
                acc[idx] += S_all[l][dy] * S_all[m][dy];
                ++idx;
            }
        }
        #pragma unroll
        for (int l = 0; l < 7; ++l) acc[28 + l] += S_all[l][dy] * rv;
    }

    // butterfly split-reduce: lane ends holding full sum of entry bitrev6(lane)
    #pragma unroll
    for (int step = 0; step < 6; ++step) {
        const int mask = 1 << step;
        const int nh = 32 >> step;
        bool hi = (tx & mask) != 0;
        #pragma unroll
        for (int i = 0; i < nh; ++i) {
            float send = hi ? acc[i] : acc[i + nh];
            float got = __shfl_xor(send, mask);
            acc[i] = (hi ? acc[i + nh] : acc[i]) + got;
        }
    }
    int ent = ((tx&1)<<5) | ((tx&2)<<3) | ((tx&4)<<1)
            | ((tx&8)>>1) | ((tx&16)>>3) | ((tx&32)>>5);
    if (ent < NENT) wsum[ent][ty] = acc[0];
    __syncthreads();
    if (tid < NENT) {
        float s = wsum[tid][0] + wsum[tid][1] + wsum[tid][2] + wsum[tid][3];
        int blockLinear = blockIdx.y*4 + blockIdx.x;
        partial[((size_t)b*NENT + tid)*RBLK + blockLinear] = s;
    }
}

// ---- stage-2: sum RBLK per-block partials per (sample, entry) in f64 ----
__global__ void reduce2_kernel(const float* __restrict__ partial,
                               double* __restrict__ M, double* __restrict__ bv) {
    int b = blockIdx.x;
    int wave = threadIdx.x >> 6;
    int lane = threadIdx.x & 63;
    for (int e = wave; e < NENT; e += 4) {
        const float* p = partial + ((size_t)b*NENT + e)*RBLK;
        double s = (double)p[lane];
        #pragma unroll
        for (int off = 32; off; off >>= 1) s += __shfl_down(s, off);
        if (lane == 0) {
            if (e < 28) M[b*28 + e] = s;
            else        bv[b*7 + (e - 28)] = s;
        }
    }
}

// ---- per-sample 7x7 solve: f64, partial pivoting, ALL-STATIC indexing ----
__global__ __launch_bounds__(64, 1) void solve_kernel(
        const double* __restrict__ M, const double* __restrict__ bv,
        float* __restrict__ K, int B) {
    int b = blockIdx.x*64 + threadIdx.x;
    if (b >= B) return;
    double A[7][8];
    int idx = 0;
    #pragma unroll
    for (int l = 0; l < 7; ++l)
        #pragma unroll
        for (int m = l; m < 7; ++m) {
            double v = M[b*28 + idx];
            A[l][m] = v;
            A[m][l] = v;
            ++idx;
        }
    #pragma unroll
    for (int l = 0; l < 7; ++l) A[l][7] = bv[b*7 + l];

    #pragma unroll
    for (int col = 0; col < 7; ++col) {
        int piv = col;
        double mx = fabs(A[col][col]);
        #pragma unroll
        for (int rr = 0; rr < 7; ++rr) {
            if (rr > col) {
                double a = fabs(A[rr][col]);
                if (a > mx) { mx = a; piv = rr; }
            }
        }
        #pragma unroll
        for (int rr = 0; rr < 7; ++rr) {
            if (rr > col) {
                bool c = (rr == piv);
                #pragma unroll
                for (int cc = 0; cc < 8; ++cc) {
                    double t0 = A[col][cc], t1 = A[rr][cc];
                    A[col][cc] = c ? t1 : t0;
                    A[rr][cc]  = c ? t0 : t1;
                }
            }
        }
        double d = A[col][col];
        #pragma unroll
        for (int rr = 0; rr < 7; ++rr) {
            if (rr > col) {
                double fct = A[rr][col] / d;
                #pragma unroll
                for (int cc = 0; cc < 8; ++cc) A[rr][cc] -= fct * A[col][cc];
            }
        }
    }
    double Kv[7];
    #pragma unroll
    for (int rr = 6; rr >= 0; --rr) {
        double s = A[rr][7];
        #pragma unroll
        for (int cc = 0; cc < 7; ++cc)
            if (cc > rr) s -= A[rr][cc] * Kv[cc];
        Kv[rr] = s / A[rr][rr];
    }
    #pragma unroll
    for (int l = 0; l < 7; ++l) K[b*7 + l] = (float)Kv[l];
}

// ---------------- x_new = x + K^T G (fp16 intermediates, 4 px/thread) ----
__global__ void update_kernel(const float* __restrict__ x, const __half* __restrict__ r,
                              const __half* __restrict__ G1, const __half* __restrict__ G2,
                              const float* __restrict__ K, float* __restrict__ out) {
    int b = blockIdx.z;
    int p4 = blockIdx.x*256 + threadIdx.x;
    float k0 = K[b*7+0], k1 = K[b*7+1], k2 = K[b*7+2], k3 = K[b*7+3];
    float k4 = K[b*7+4], k5 = K[b*7+5], k6 = K[b*7+6];
    size_t q  = (size_t)b*(NPIX/4) + p4;
    size_t e0 = ((size_t)b*3*NPIX) + (size_t)p4*4;
    size_t er = ((size_t)b*NPIX) + (size_t)p4*4;

    float4 xv = ((const float4*)x)[q];
    float4 rv = load_h4(r + er);
    float4 a  = load_h4(G1 + e0);
    float4 bb = load_h4(G1 + e0 + NPIX);
    float4 c  = load_h4(G1 + e0 + 2*(size_t)NPIX);
    float4 d  = load_h4(G2 + e0);
    float4 e  = load_h4(G2 + e0 + NPIX);
    float4 g  = load_h4(G2 + e0 + 2*(size_t)NPIX);
    float4 o;
    o.x = xv.x + k0*rv.x + k1*a.x + k2*bb.x + k3*c.x + k4*d.x + k5*e.x + k6*g.x;
    o.y = xv.y + k0*rv.y + k1*a.y + k2*bb.y + k3*c.y + k4*d.y + k5*e.y + k6*g.y;
    o.z = xv.z + k0*rv.z + k1*a.z + k2*bb.z + k3*c.z + k4*d.z + k5*e.z + k6*g.z;
    o.w = xv.w + k0*rv.w + k1*a.w + k2*bb.w + k3*c.w + k4*d.w + k5*e.w + k6*g.w;
    ((float4*)out)[q] = o;
}

extern "C" void kernel_launch(void* const* d_in, const int* in_sizes, int n_in,
                              void* d_out, int out_size, void* d_ws, size_t ws_size,
                              hipStream_t stream) {
    const float* x       = (const float*)d_in[0];
    const float* f       = (const float*)d_in[1];
    const float* kernelA = (const float*)d_in[2];
    const float* fc1_w1  = (const float*)d_in[3];
    const float* fc1_b1  = (const float*)d_in[4];
    const float* fc1_w2  = (const float*)d_in[5];
    const float* fc1_b2  = (const float*)d_in[6];
    const float* fc2_w1  = (const float*)d_in[7];
    const float* fc2_b1  = (const float*)d_in[8];
    const float* fc2_w2  = (const float*)d_in[9];
    const float* fc2_b2  = (const float*)d_in[10];
    float* out = (float*)d_out;

    const int B = in_sizes[2] / 9;

    // workspace: doubles, fp32, packed half2 weights, then fp16 planes.
    double*  Mws = (double*)d_ws;                    // B*28
    double*  bws = Mws + (size_t)B*28;               // B*7
    float*   w1  = (float*)(bws + (size_t)B*7);      // B*147
    float*   Kv  = w1 + (size_t)B*147;               // B*7
    float*   partial = Kv + (size_t)B*7;             // B*NENT*RBLK
    half2r*  w2p = (half2r*)(partial + (size_t)B*NENT*RBLK);  // B*504 (4B each)
    __half*  r   = (__half*)(w2p + (size_t)B*504);   // B*NPIX
    __half*  G1  = r  + (size_t)B*NPIX;              // B*3*NPIX
    __half*  G2  = G1 + (size_t)B*3*NPIX;            // B*3*NPIX

    dim3 cblk(64, 4);
    dim3 rgrd(MU/64, MU/16, B);    // reduce
    dim3 g1grd(MU/128, MU/16, B);  // res_g1
    dim3 g2grd(MU/128, MU/8, B);   // conv7_g2

    hipLaunchKernelGGL(mlp_kernel, dim3(B), dim3(256), 0, stream,
                       kernelA, fc1_w1, fc1_b1, fc1_w2, fc1_b2,
                       fc2_w1, fc2_b1, fc2_w2, fc2_b2, w1, w2p);
    hipLaunchKernelGGL(res_g1_kernel, g1grd, cblk, 0, stream, x, f, kernelA, w1, r, G1);
    hipLaunchKernelGGL(conv7_g2, g2grd, cblk, 0, stream, G1, w2p, G2);
    hipLaunchKernelGGL(reduce_kernel, rgrd, cblk, 0, stream, r, G1, G2, kernelA, partial);
    hipLaunchKernelGGL(reduce2_kernel, dim3(B), dim3(256), 0, stream, partial, Mws, bws);
    hipLaunchKernelGGL(solve_kernel, dim3((B + 63)/64), dim3(64), 0, stream, Mws, bws, Kv, B);
    hipLaunchKernelGGL(update_kernel, dim3(NPIX/1024, 1, B), dim3(256), 0, stream,
                       x, r, G1, G2, Kv, out);
}

// Round 21
// 168.674 us; speedup vs baseline: 1.2658x; 1.2658x over previous
//
#include <hip/hip_runtime.h>
#include <hip/hip_fp16.h>

#define MU 256
#define NPIX (MU*MU)
#define ML 3
#define KS 7
#define LCH 7
#define NENT 35   // 28 upper-tri M entries + 7 b entries
#define RBLK 128  // partial blocks per sample in reduce stage-1 (grid 4x32)

typedef _Float16 half2r __attribute__((ext_vector_type(2)));

__device__ __forceinline__ float dot2f(half2r a, half2r b, float c) {
#if __has_builtin(__builtin_amdgcn_fdot2)
    return __builtin_amdgcn_fdot2(a, b, c, false);
#else
    return c + (float)a.x*(float)b.x + (float)a.y*(float)b.y;
#endif
}

// load 4 consecutive halfs (8B) -> float4
__device__ __forceinline__ float4 load_h4(const __half* p) {
    __half2 a = *(const __half2*)p;
    __half2 b = *(const __half2*)(p + 2);
    float2 fa = __half22float2(a), fb = __half22float2(b);
    return make_float4(fa.x, fa.y, fb.x, fb.y);
}

// ---------------- MLP: per-sample dynamic kernels ----------------
// Packs w2 into the 8 half2 alignments needed by the dot2 conv:
//   group g = (c*7+i)*3+co (0..62), entries p=0..7:
//   p<4  (even set, accA): (0,w0),(w1,w2),(w3,w4),(w5,w6)
//   p>=4 (odd  set, accB): (w0,w1),(w2,w3),(w4,w5),(w6,0)
__global__ void mlp_kernel(const float* __restrict__ kernelA,
                           const float* __restrict__ fc1_w1, const float* __restrict__ fc1_b1,
                           const float* __restrict__ fc1_w2, const float* __restrict__ fc1_b2,
                           const float* __restrict__ fc2_w1, const float* __restrict__ fc2_b1,
                           const float* __restrict__ fc2_w2, const float* __restrict__ fc2_b2,
                           float* __restrict__ w1_out, half2r* __restrict__ w2p) {
    int b = blockIdx.x;
    int t = threadIdx.x;
    __shared__ float kA[9];
    __shared__ float h1[200], h2[200];
    __shared__ float w2s[441];
    if (t < 9) kA[t] = kernelA[b*9 + t];
    __syncthreads();
    if (t < 200) {
        float s1 = fc1_b1[t], s2 = fc2_b1[t];
        #pragma unroll
        for (int i = 0; i < 9; ++i) {
            s1 += kA[i] * fc1_w1[i*200 + t];
            s2 += kA[i] * fc2_w1[i*200 + t];
        }
        h1[t] = fmaxf(s1, 0.f);
        h2[t] = fmaxf(s2, 0.f);
    }
    __syncthreads();
    if (t < 147) {
        float s = fc1_b2[t];
        for (int i = 0; i < 200; ++i) s += h1[i] * fc1_w2[i*147 + t];
        w1_out[b*147 + t] = s;
    }
    for (int o = t; o < 441; o += 256) {
        float s = fc2_b2[o];
        for (int i = 0; i < 200; ++i) s += h2[i] * fc2_w2[i*441 + o];
        w2s[o] = s;
    }
    __syncthreads();
    for (int u = t; u < 504; u += 256) {
        int grp = u / 8, p = u % 8;
        int co = grp % 3, i = (grp / 3) % 7, c = grp / 21;
        const float* w = &w2s[co*147 + c*49 + i*7];   // w[j], j=0..6
        float lo, hi;
        if (p < 4) { lo = (p == 0) ? 0.f : w[2*p - 1]; hi = w[2*p]; }
        else       { int q = p - 4; lo = w[2*q]; hi = (q == 3) ? 0.f : w[2*q + 1]; }
        half2r hp; hp.x = (_Float16)lo; hp.y = (_Float16)hi;
        w2p[(size_t)b*504 + u] = hp;
    }
}

// ---- FUSED: r = f - conv3x3(x) into LDS (fp32), interior r written as
//      fp16, then conv7x7 1->3ch from LDS; G1 written as fp16. ----
__global__ __launch_bounds__(256) void res_g1_kernel(
        const float* __restrict__ x, const float* __restrict__ f,
        const float* __restrict__ kA, const float* __restrict__ w1,
        __half* __restrict__ r, __half* __restrict__ G1) {
    int b = blockIdx.z;
    __shared__ float xt[24][144];
    __shared__ float rt[22][136];
    int tx = threadIdx.x;
    int ty = threadIdx.y;
    int tid = ty*64 + tx;
    int x0 = blockIdx.x*128, y0 = blockIdx.y*16;
    const float* xb = x + (size_t)b*NPIX;
    const float* fb = f + (size_t)b*NPIX;
    const float* wgt = w1 + (size_t)b*147;
    float k[9];
    #pragma unroll
    for (int i = 0; i < 9; ++i) k[i] = kA[b*9 + i];

    for (int u = tid; u < 24*36; u += 256) {
        int row = u / 36, q4 = u % 36;
        int yy = y0 + row - 4;
        int xx = x0 - 8 + q4*4;
        float4 vv = make_float4(0.f, 0.f, 0.f, 0.f);
        if (yy >= 0 && yy < MU && xx >= 0 && xx < MU)
            vv = *(const float4*)(xb + yy*MU + xx);
        *(float4*)&xt[row][q4*4] = vv;
    }
    __syncthreads();

    for (int u = tid; u < 22*34; u += 256) {
        int row = u / 34, c4 = u % 34;
        int Y = y0 - 3 + row;
        int X = x0 - 4 + 4*c4;
        bool inb = (Y >= 0 && Y < MU && X >= 0 && X < MU);
        float4 fv = make_float4(0.f, 0.f, 0.f, 0.f);
        if (inb) fv = *(const float4*)(fb + Y*MU + X);
        float fr[4] = {fv.x, fv.y, fv.z, fv.w};
        float rr[4];
        #pragma unroll
        for (int cc = 0; cc < 4; ++cc) {
            float s = 0.f;
            #pragma unroll
            for (int di = 0; di < 3; ++di)
                #pragma unroll
                for (int dj = 0; dj < 3; ++dj)
                    s += xt[row + di][4*c4 + 3 + cc + dj] * k[di*3 + dj];
            rr[cc] = inb ? (fr[cc] - s) : 0.f;
        }
        *(float4*)&rt[row][4*c4] = make_float4(rr[0], rr[1], rr[2], rr[3]);
    }
    __syncthreads();

    float accA[3][4], accB[3][4];
    #pragma unroll
    for (int co = 0; co < 3; ++co)
        #pragma unroll
        for (int dy = 0; dy < 4; ++dy) { accA[co][dy] = 0.f; accB[co][dy] = 0.f; }

    int ry = ty*4;
    #pragma unroll
    for (int ir = 0; ir < 10; ++ir) {
        float v[10];
        #pragma unroll
        for (int h = 0; h < 5; ++h)
            *(float2*)&v[h*2] = *(float2*)&rt[ry + ir][2*tx + h*2];
        #pragma unroll
        for (int dy = 0; dy < 4; ++dy) {
            int i = ir - dy;
            if (i >= 0 && i <= 6) {
                #pragma unroll
                for (int co = 0; co < 3; ++co)
                    #pragma unroll
                    for (int j = 0; j < 7; ++j) {
                        float w = wgt[(co*7 + i)*7 + j];
                        accA[co][dy] += v[1 + j] * w;
                        accB[co][dy] += v[2 + j] * w;
                    }
            }
        }
    }
    #pragma unroll
    for (int dy = 0; dy < 4; ++dy) {
        size_t pr = (size_t)b*NPIX + (size_t)(y0 + ry + dy)*MU + x0 + 2*tx;
        float2 rv2 = *(float2*)&rt[3 + ry + dy][4 + 2*tx];
        *(__half2*)&r[pr] = __float22half2_rn(rv2);
        size_t p = (size_t)b*3*NPIX + (size_t)(y0 + ry + dy)*MU + x0 + 2*tx;
        #pragma unroll
        for (int co = 0; co < 3; ++co)
            *(__half2*)&G1[p + (size_t)co*NPIX] =
                __float22half2_rn(make_float2(accA[co][dy], accB[co][dy]));
    }
}

// ---- conv7x7 3->3ch via v_dot2_f32_f16: fp16 LDS tile (11.4 KB),
//      fp32 accumulators. ----
__global__ __launch_bounds__(256) void conv7_g2(
        const __half* __restrict__ G1, const half2r* __restrict__ w2p,
        __half* __restrict__ G2) {
    int b = blockIdx.z;
    __shared__ _Float16 tile[3][14][136];
    int tx = threadIdx.x;
    int ty = threadIdx.y;
    int tid = ty*64 + tx;
    int x0 = blockIdx.x*128, y0 = blockIdx.y*8;
    const __half* g1b = G1 + (size_t)b*3*NPIX;
    const half2r* wp = w2p + (size_t)b*504;

    for (int u = tid; u < 3*14*34; u += 256) {
        int c = u / (14*34);
        int rem = u % (14*34);
        int row = rem / 34, q4 = rem % 34;
        int yy = y0 + row - 3;
        int xx = x0 - 4 + q4*4;
        ushort4 vv = make_ushort4(0, 0, 0, 0);
        if (yy >= 0 && yy < MU && xx >= 0 && xx < MU)
            vv = *(const ushort4*)(g1b + (size_t)c*NPIX + yy*MU + xx);
        *(ushort4*)&tile[c][row][q4*4] = vv;
    }
    __syncthreads();

    float accA[3][2], accB[3][2];
    #pragma unroll
    for (int co = 0; co < 3; ++co)
        #pragma unroll
        for (int dy = 0; dy < 2; ++dy) { accA[co][dy] = 0.f; accB[co][dy] = 0.f; }

    int ry = ty*2;
    #pragma unroll
    for (int c = 0; c < 3; ++c) {
        #pragma unroll
        for (int ir = 0; ir < 8; ++ir) {
            half2r P[5];
            #pragma unroll
            for (int q = 0; q < 5; ++q)
                P[q] = *(const half2r*)&tile[c][ry + ir][2*tx + 2*q];
            #pragma unroll
            for (int dy = 0; dy < 2; ++dy) {
                int i = ir - dy;
                if (i >= 0 && i <= 6) {
                    #pragma unroll
                    for (int co = 0; co < 3; ++co) {
                        const half2r* wv = wp + ((c*7 + i)*3 + co)*8;
                        accA[co][dy] = dot2f(P[0], wv[0], accA[co][dy]);
                        accA[co][dy] = dot2f(P[1], wv[1], accA[co][dy]);
                        accA[co][dy] = dot2f(P[2], wv[2], accA[co][dy]);
                        accA[co][dy] = dot2f(P[3], wv[3], accA[co][dy]);
                        accB[co][dy] = dot2f(P[1], wv[4], accB[co][dy]);
                        accB[co][dy] = dot2f(P[2], wv[5], accB[co][dy]);
                        accB[co][dy] = dot2f(P[3], wv[6], accB[co][dy]);
                        accB[co][dy] = dot2f(P[4], wv[7], accB[co][dy]);
                    }
                }
            }
        }
    }
    #pragma unroll
    for (int dy = 0; dy < 2; ++dy) {
        size_t p = (size_t)b*3*NPIX + (size_t)(y0 + ry + dy)*MU + x0 + 2*tx;
        #pragma unroll
        for (int co = 0; co < 3; ++co)
            *(__half2*)&G2[p + (size_t)co*NPIX] =
                __float22half2_rn(make_float2(accA[co][dy], accB[co][dy]));
    }
}

// ---- S = depthwise3x3(G, kernelA); stage-1 Gram partials.
//      fp32 LDS tile, HALF-HEIGHT [7][10][72] = 20.2 KB -> 7 blocks/CU,
//      2 output rows/thread, butterfly split-reduction. ----
__global__ __launch_bounds__(256, 4) void reduce_kernel(
        const __half* __restrict__ r, const __half* __restrict__ G1,
        const __half* __restrict__ G2, const float* __restrict__ kA,
        float* __restrict__ partial) {
    int b = blockIdx.z;
    __shared__ float tile[7][10][72];
    __shared__ float wsum[NENT][4];
    int tx = threadIdx.x;          // 0..63 = lane; wave == one ty
    int ty = threadIdx.y;          // 0..3
    int tid = ty*64 + tx;
    float k[9];
    #pragma unroll
    for (int i = 0; i < 9; ++i) k[i] = kA[b*9 + i];

    const __half* srcs[7] = {
        r  + (size_t)b*NPIX,
        G1 + (size_t)b*3*NPIX, G1 + (size_t)b*3*NPIX + NPIX, G1 + (size_t)b*3*NPIX + 2*NPIX,
        G2 + (size_t)b*3*NPIX, G2 + (size_t)b*3*NPIX + NPIX, G2 + (size_t)b*3*NPIX + 2*NPIX
    };

    int x0 = blockIdx.x*64;
    int ysub = blockIdx.y*8;       // 8 output rows per block

    #pragma unroll
    for (int c = 0; c < 7; ++c) {
        const __half* src = srcs[c];
        for (int u = tid; u < 10*18; u += 256) {
            int row = u / 18, q4 = u % 18;
            int yy = ysub + row - 1;
            int xx = x0 - 4 + q4*4;
            float4 vv = make_float4(0.f, 0.f, 0.f, 0.f);
            if (yy >= 0 && yy < MU && xx >= 0 && xx < MU)
                vv = load_h4(src + yy*MU + xx);
            *(float4*)&tile[c][row][q4*4] = vv;
        }
    }
    __syncthreads();

    float acc[64];
    #pragma unroll
    for (int e = 0; e < 64; ++e) acc[e] = 0.f;

    int ry = ty*2;   // output rows ry, ry+1 (tile rows ry..ry+3)
    float S_all[7][2];
    #pragma unroll
    for (int c = 0; c < 7; ++c) {
        float S0 = 0.f, S1 = 0.f;
        #pragma unroll
        for (int t = 0; t < 4; ++t) {
            float v0 = tile[c][ry + t][tx + 3];
            float v1 = tile[c][ry + t][tx + 4];
            float v2 = tile[c][ry + t][tx + 5];
            float e0 = v0*k[0] + v1*k[1] + v2*k[2];
            float e1 = v0*k[3] + v1*k[4] + v2*k[5];
            float e2 = v0*k[6] + v1*k[7] + v2*k[8];
            if (t == 0) { S0 += e0; }
            if (t == 1) { S0 += e1; S1 += e0; }
            if (t == 2) { S0 += e2; S1 += e1; }
            if (t == 3) {           S1 += e2; }
        }
        S_all[c][0] = S0; S_all[c][1] = S1;
    }
    #pragma unroll
    for (int dy = 0; dy < 2; ++dy) {
        float rv = tile[0][ry + dy + 1][tx + 4];
        int idx = 0;
        #pragma unroll
        for (int l = 0; l < 7; ++l) {
            #pragma unroll
            for (int m = l; m < 7; ++m) {
                acc[idx] += S_all[l][dy] * S_all[m][dy];
                ++idx;
            }
        }
        #pragma unroll
        for (int l = 0; l < 7; ++l) acc[28 + l] += S_all[l][dy] * rv;
    }

    // butterfly split-reduce: lane ends holding full sum of entry bitrev6(lane)
    #pragma unroll
    for (int step = 0; step < 6; ++step) {
        const int mask = 1 << step;
        const int nh = 32 >> step;
        bool hi = (tx & mask) != 0;
        #pragma unroll
        for (int i = 0; i < nh; ++i) {
            float send = hi ? acc[i] : acc[i + nh];
            float got = __shfl_xor(send, mask);
            acc[i] = (hi ? acc[i + nh] : acc[i]) + got;
        }
    }
    int ent = ((tx&1)<<5) | ((tx&2)<<3) | ((tx&4)<<1)
            | ((tx&8)>>1) | ((tx&16)>>3) | ((tx&32)>>5);
    if (ent < NENT) wsum[ent][ty] = acc[0];
    __syncthreads();
    if (tid < NENT) {
        float s = wsum[tid][0] + wsum[tid][1] + wsum[tid][2] + wsum[tid][3];
        int blockLinear = blockIdx.y*4 + blockIdx.x;   // 0..127
        partial[((size_t)b*NENT + tid)*RBLK + blockLinear] = s;
    }
}

// ---- stage-2: sum RBLK (=128) per-block partials per (sample, entry) ----
__global__ void reduce2_kernel(const float* __restrict__ partial,
                               double* __restrict__ M, double* __restrict__ bv) {
    int b = blockIdx.x;
    int wave = threadIdx.x >> 6;
    int lane = threadIdx.x & 63;
    for (int e = wave; e < NENT; e += 4) {
        const float* p = partial + ((size_t)b*NENT + e)*RBLK;
        double s = (double)p[lane] + (double)p[lane + 64];
        #pragma unroll
        for (int off = 32; off; off >>= 1) s += __shfl_down(s, off);
        if (lane == 0) {
            if (e < 28) M[b*28 + e] = s;
            else        bv[b*7 + (e - 28)] = s;
        }
    }
}

// ---- per-sample 7x7 solve: f64, partial pivoting, ALL-STATIC indexing ----
__global__ __launch_bounds__(64, 1) void solve_kernel(
        const double* __restrict__ M, const double* __restrict__ bv,
        float* __restrict__ K, int B) {
    int b = blockIdx.x*64 + threadIdx.x;
    if (b >= B) return;
    double A[7][8];
    int idx = 0;
    #pragma unroll
    for (int l = 0; l < 7; ++l)
        #pragma unroll
        for (int m = l; m < 7; ++m) {
            double v = M[b*28 + idx];
            A[l][m] = v;
            A[m][l] = v;
            ++idx;
        }
    #pragma unroll
    for (int l = 0; l < 7; ++l) A[l][7] = bv[b*7 + l];

    #pragma unroll
    for (int col = 0; col < 7; ++col) {
        int piv = col;
        double mx = fabs(A[col][col]);
        #pragma unroll
        for (int rr = 0; rr < 7; ++rr) {
            if (rr > col) {
                double a = fabs(A[rr][col]);
                if (a > mx) { mx = a; piv = rr; }
            }
        }
        #pragma unroll
        for (int rr = 0; rr < 7; ++rr) {
            if (rr > col) {
                bool c = (rr == piv);
                #pragma unroll
                for (int cc = 0; cc < 8; ++cc) {
                    double t0 = A[col][cc], t1 = A[rr][cc];
                    A[col][cc] = c ? t1 : t0;
                    A[rr][cc]  = c ? t0 : t1;
                }
            }
        }
        double d = A[col][col];
        #pragma unroll
        for (int rr = 0; rr < 7; ++rr) {
            if (rr > col) {
                double fct = A[rr][col] / d;
                #pragma unroll
                for (int cc = 0; cc < 8; ++cc) A[rr][cc] -= fct * A[col][cc];
            }
        }
    }
    double Kv[7];
    #pragma unroll
    for (int rr = 6; rr >= 0; --rr) {
        double s = A[rr][7];
        #pragma unroll
        for (int cc = 0; cc < 7; ++cc)
            if (cc > rr) s -= A[rr][cc] * Kv[cc];
        Kv[rr] = s / A[rr][rr];
    }
    #pragma unroll
    for (int l = 0; l < 7; ++l) K[b*7 + l] = (float)Kv[l];
}

// ---------------- x_new = x + K^T G (fp16 intermediates, 4 px/thread) ----
__global__ void update_kernel(const float* __restrict__ x, const __half* __restrict__ r,
                              const __half* __restrict__ G1, const __half* __restrict__ G2,
                              const float* __restrict__ K, float* __restrict__ out) {
    int b = blockIdx.z;
    int p4 = blockIdx.x*256 + threadIdx.x;
    float k0 = K[b*7+0], k1 = K[b*7+1], k2 = K[b*7+2], k3 = K[b*7+3];
    float k4 = K[b*7+4], k5 = K[b*7+5], k6 = K[b*7+6];
    size_t q  = (size_t)b*(NPIX/4) + p4;
    size_t e0 = ((size_t)b*3*NPIX) + (size_t)p4*4;
    size_t er = ((size_t)b*NPIX) + (size_t)p4*4;

    float4 xv = ((const float4*)x)[q];
    float4 rv = load_h4(r + er);
    float4 a  = load_h4(G1 + e0);
    float4 bb = load_h4(G1 + e0 + NPIX);
    float4 c  = load_h4(G1 + e0 + 2*(size_t)NPIX);
    float4 d  = load_h4(G2 + e0);
    float4 e  = load_h4(G2 + e0 + NPIX);
    float4 g  = load_h4(G2 + e0 + 2*(size_t)NPIX);
    float4 o;
    o.x = xv.x + k0*rv.x + k1*a.x + k2*bb.x + k3*c.x + k4*d.x + k5*e.x + k6*g.x;
    o.y = xv.y + k0*rv.y + k1*a.y + k2*bb.y + k3*c.y + k4*d.y + k5*e.y + k6*g.y;
    o.z = xv.z + k0*rv.z + k1*a.z + k2*bb.z + k3*c.z + k4*d.z + k5*e.z + k6*g.z;
    o.w = xv.w + k0*rv.w + k1*a.w + k2*bb.w + k3*c.w + k4*d.w + k5*e.w + k6*g.w;
    ((float4*)out)[q] = o;
}

extern "C" void kernel_launch(void* const* d_in, const int* in_sizes, int n_in,
                              void* d_out, int out_size, void* d_ws, size_t ws_size,
                              hipStream_t stream) {
    const float* x       = (const float*)d_in[0];
    const float* f       = (const float*)d_in[1];
    const float* kernelA = (const float*)d_in[2];
    const float* fc1_w1  = (const float*)d_in[3];
    const float* fc1_b1  = (const float*)d_in[4];
    const float* fc1_w2  = (const float*)d_in[5];
    const float* fc1_b2  = (const float*)d_in[6];
    const float* fc2_w1  = (const float*)d_in[7];
    const float* fc2_b1  = (const float*)d_in[8];
    const float* fc2_w2  = (const float*)d_in[9];
    const float* fc2_b2  = (const float*)d_in[10];
    float* out = (float*)d_out;

    const int B = in_sizes[2] / 9;

    // workspace: doubles, fp32, packed half2 weights, then fp16 planes.
    double*  Mws = (double*)d_ws;                    // B*28
    double*  bws = Mws + (size_t)B*28;               // B*7
    float*   w1  = (float*)(bws + (size_t)B*7);      // B*147
    float*   Kv  = w1 + (size_t)B*147;               // B*7
    float*   partial = Kv + (size_t)B*7;             // B*NENT*RBLK
    half2r*  w2p = (half2r*)(partial + (size_t)B*NENT*RBLK);  // B*504 (4B each)
    __half*  r   = (__half*)(w2p + (size_t)B*504);   // B*NPIX
    __half*  G1  = r  + (size_t)B*NPIX;              // B*3*NPIX
    __half*  G2  = G1 + (size_t)B*3*NPIX;            // B*3*NPIX

    dim3 cblk(64, 4);
    dim3 rgrd(MU/64, MU/8, B);     // reduce (4 x 32 x B)
    dim3 g1grd(MU/128, MU/16, B);  // res_g1
    dim3 g2grd(MU/128, MU/8, B);   // conv7_g2

    hipLaunchKernelGGL(mlp_kernel, dim3(B), dim3(256), 0, stream,
                       kernelA, fc1_w1, fc1_b1, fc1_w2, fc1_b2,
                       fc2_w1, fc2_b1, fc2_w2, fc2_b2, w1, w2p);
    hipLaunchKernelGGL(res_g1_kernel, g1grd, cblk, 0, stream, x, f, kernelA, w1, r, G1);
    hipLaunchKernelGGL(conv7_g2, g2grd, cblk, 0, stream, G1, w2p, G2);
    hipLaunchKernelGGL(reduce_kernel, rgrd, cblk, 0, stream, r, G1, G2, kernelA, partial);
    hipLaunchKernelGGL(reduce2_kernel, dim3(B), dim3(256), 0, stream, partial, Mws, bws);
    hipLaunchKernelGGL(solve_kernel, dim3((B + 63)/64), dim3(64), 0, stream, Mws, bws, Kv, B);
    hipLaunchKernelGGL(update_kernel, dim3(NPIX/1024, 1, B), dim3(256), 0, stream,
                       x, r, G1, G2, Kv, out);
}

// Round 22
// 165.693 us; speedup vs baseline: 1.2886x; 1.0180x over previous
//
#include <hip/hip_runtime.h>
#include <hip/hip_fp16.h>

#define MU 256
#define NPIX (MU*MU)
#define ML 3
#define KS 7
#define LCH 7
#define NENT 35   // 28 upper-tri M entries + 7 b entries
#define RBLK 128  // partial blocks per sample in reduce stage-1 (grid 4x32)

typedef _Float16 half2r __attribute__((ext_vector_type(2)));

__device__ __forceinline__ float dot2f(half2r a, half2r b, float c) {
#if __has_builtin(__builtin_amdgcn_fdot2)
    return __builtin_amdgcn_fdot2(a, b, c, false);
#else
    return c + (float)a.x*(float)b.x + (float)a.y*(float)b.y;
#endif
}

// load 4 consecutive halfs (8B) -> float4
__device__ __forceinline__ float4 load_h4(const __half* p) {
    __half2 a = *(const __half2*)p;
    __half2 b = *(const __half2*)(p + 2);
    float2 fa = __half22float2(a), fb = __half22float2(b);
    return make_float4(fa.x, fa.y, fb.x, fb.y);
}

// ---------------- MLP: per-sample dynamic kernels ----------------
// Packs w1 and w2 into the 8 half2 alignments needed by the dot2 convs:
//   per group, entries p=0..7:
//   p<4  (even set, accA): (0,w0),(w1,w2),(w3,w4),(w5,w6)
//   p>=4 (odd  set, accB): (w0,w1),(w2,w3),(w4,w5),(w6,0)
//   w1 groups: g = i*3+co (21);  w2 groups: g = (c*7+i)*3+co (63)
__global__ void mlp_kernel(const float* __restrict__ kernelA,
                           const float* __restrict__ fc1_w1, const float* __restrict__ fc1_b1,
                           const float* __restrict__ fc1_w2, const float* __restrict__ fc1_b2,
                           const float* __restrict__ fc2_w1, const float* __restrict__ fc2_b1,
                           const float* __restrict__ fc2_w2, const float* __restrict__ fc2_b2,
                           half2r* __restrict__ w1p, half2r* __restrict__ w2p) {
    int b = blockIdx.x;
    int t = threadIdx.x;
    __shared__ float kA[9];
    __shared__ float h1[200], h2[200];
    __shared__ float w1s[147];
    __shared__ float w2s[441];
    if (t < 9) kA[t] = kernelA[b*9 + t];
    __syncthreads();
    if (t < 200) {
        float s1 = fc1_b1[t], s2 = fc2_b1[t];
        #pragma unroll
        for (int i = 0; i < 9; ++i) {
            s1 += kA[i] * fc1_w1[i*200 + t];
            s2 += kA[i] * fc2_w1[i*200 + t];
        }
        h1[t] = fmaxf(s1, 0.f);
        h2[t] = fmaxf(s2, 0.f);
    }
    __syncthreads();
    if (t < 147) {
        float s = fc1_b2[t];
        for (int i = 0; i < 200; ++i) s += h1[i] * fc1_w2[i*147 + t];
        w1s[t] = s;
    }
    for (int o = t; o < 441; o += 256) {
        float s = fc2_b2[o];
        for (int i = 0; i < 200; ++i) s += h2[i] * fc2_w2[i*441 + o];
        w2s[o] = s;
    }
    __syncthreads();
    // pack w1: 21 groups x 8
    for (int u = t; u < 168; u += 256) {
        int grp = u / 8, p = u % 8;
        int co = grp % 3, i = grp / 3;
        const float* w = &w1s[co*49 + i*7];
        float lo, hi;
        if (p < 4) { lo = (p == 0) ? 0.f : w[2*p - 1]; hi = w[2*p]; }
        else       { int q = p - 4; lo = w[2*q]; hi = (q == 3) ? 0.f : w[2*q + 1]; }
        half2r hp; hp.x = (_Float16)lo; hp.y = (_Float16)hi;
        w1p[(size_t)b*168 + u] = hp;
    }
    // pack w2: 63 groups x 8
    for (int u = t; u < 504; u += 256) {
        int grp = u / 8, p = u % 8;
        int co = grp % 3, i = (grp / 3) % 7, c = grp / 21;
        const float* w = &w2s[co*147 + c*49 + i*7];
        float lo, hi;
        if (p < 4) { lo = (p == 0) ? 0.f : w[2*p - 1]; hi = w[2*p]; }
        else       { int q = p - 4; lo = w[2*q]; hi = (q == 3) ? 0.f : w[2*q + 1]; }
        half2r hp; hp.x = (_Float16)lo; hp.y = (_Float16)hi;
        w2p[(size_t)b*504 + u] = hp;
    }
}

// ---- FUSED: r = f - conv3x3(x) into LDS as fp16 (same rounding as the
//      global r write), then conv7x7 1->3ch via v_dot2_f32_f16. ----
__global__ __launch_bounds__(256) void res_g1_kernel(
        const float* __restrict__ x, const float* __restrict__ f,
        const float* __restrict__ kA, const half2r* __restrict__ w1p,
        __half* __restrict__ r, __half* __restrict__ G1) {
    int b = blockIdx.z;
    __shared__ float xt[24][144];        // 13.8 KB
    __shared__ _Float16 rt[22][136];     // 6.0 KB
    int tx = threadIdx.x;
    int ty = threadIdx.y;
    int tid = ty*64 + tx;
    int x0 = blockIdx.x*128, y0 = blockIdx.y*16;
    const float* xb = x + (size_t)b*NPIX;
    const float* fb = f + (size_t)b*NPIX;
    const half2r* wp = w1p + (size_t)b*168;   // uniform -> SGPR loads
    float k[9];
    #pragma unroll
    for (int i = 0; i < 9; ++i) k[i] = kA[b*9 + i];

    for (int u = tid; u < 24*36; u += 256) {
        int row = u / 36, q4 = u % 36;
        int yy = y0 + row - 4;
        int xx = x0 - 8 + q4*4;
        float4 vv = make_float4(0.f, 0.f, 0.f, 0.f);
        if (yy >= 0 && yy < MU && xx >= 0 && xx < MU)
            vv = *(const float4*)(xb + yy*MU + xx);
        *(float4*)&xt[row][q4*4] = vv;
    }
    __syncthreads();

    for (int u = tid; u < 22*34; u += 256) {
        int row = u / 34, c4 = u % 34;
        int Y = y0 - 3 + row;
        int X = x0 - 4 + 4*c4;
        bool inb = (Y >= 0 && Y < MU && X >= 0 && X < MU);
        float4 fv = make_float4(0.f, 0.f, 0.f, 0.f);
        if (inb) fv = *(const float4*)(fb + Y*MU + X);
        float fr[4] = {fv.x, fv.y, fv.z, fv.w};
        float rr[4];
        #pragma unroll
        for (int cc = 0; cc < 4; ++cc) {
            float s = 0.f;
            #pragma unroll
            for (int di = 0; di < 3; ++di)
                #pragma unroll
                for (int dj = 0; dj < 3; ++dj)
                    s += xt[row + di][4*c4 + 3 + cc + dj] * k[di*3 + dj];
            rr[cc] = inb ? (fr[cc] - s) : 0.f;
        }
        __half2 h01 = __float22half2_rn(make_float2(rr[0], rr[1]));
        __half2 h23 = __float22half2_rn(make_float2(rr[2], rr[3]));
        *(__half2*)&rt[row][4*c4]     = h01;
        *(__half2*)&rt[row][4*c4 + 2] = h23;
    }
    __syncthreads();

    float accA[3][4], accB[3][4];
    #pragma unroll
    for (int co = 0; co < 3; ++co)
        #pragma unroll
        for (int dy = 0; dy < 4; ++dy) { accA[co][dy] = 0.f; accB[co][dy] = 0.f; }

    int ry = ty*4;
    #pragma unroll
    for (int ir = 0; ir < 10; ++ir) {
        half2r P[5];
        #pragma unroll
        for (int q = 0; q < 5; ++q)
            P[q] = *(const half2r*)&rt[ry + ir][2*tx + 2*q];
        #pragma unroll
        for (int dy = 0; dy < 4; ++dy) {
            int i = ir - dy;
            if (i >= 0 && i <= 6) {
                #pragma unroll
                for (int co = 0; co < 3; ++co) {
                    const half2r* wv = wp + (i*3 + co)*8;
                    accA[co][dy] = dot2f(P[0], wv[0], accA[co][dy]);
                    accA[co][dy] = dot2f(P[1], wv[1], accA[co][dy]);
                    accA[co][dy] = dot2f(P[2], wv[2], accA[co][dy]);
                    accA[co][dy] = dot2f(P[3], wv[3], accA[co][dy]);
                    accB[co][dy] = dot2f(P[1], wv[4], accB[co][dy]);
                    accB[co][dy] = dot2f(P[2], wv[5], accB[co][dy]);
                    accB[co][dy] = dot2f(P[3], wv[6], accB[co][dy]);
                    accB[co][dy] = dot2f(P[4], wv[7], accB[co][dy]);
                }
            }
        }
    }
    #pragma unroll
    for (int dy = 0; dy < 4; ++dy) {
        size_t pr = (size_t)b*NPIX + (size_t)(y0 + ry + dy)*MU + x0 + 2*tx;
        *(__half2*)&r[pr] = *(__half2*)&rt[3 + ry + dy][4 + 2*tx];   // bit-copy
        size_t p = (size_t)b*3*NPIX + (size_t)(y0 + ry + dy)*MU + x0 + 2*tx;
        #pragma unroll
        for (int co = 0; co < 3; ++co)
            *(__half2*)&G1[p + (size_t)co*NPIX] =
                __float22half2_rn(make_float2(accA[co][dy], accB[co][dy]));
    }
}

// ---- conv7x7 3->3ch via v_dot2_f32_f16: fp16 LDS tile (11.4 KB),
//      fp32 accumulators. ----
__global__ __launch_bounds__(256) void conv7_g2(
        const __half* __restrict__ G1, const half2r* __restrict__ w2p,
        __half* __restrict__ G2) {
    int b = blockIdx.z;
    __shared__ _Float16 tile[3][14][136];
    int tx = threadIdx.x;
    int ty = threadIdx.y;
    int tid = ty*64 + tx;
    int x0 = blockIdx.x*128, y0 = blockIdx.y*8;
    const __half* g1b = G1 + (size_t)b*3*NPIX;
    const half2r* wp = w2p + (size_t)b*504;

    for (int u = tid; u < 3*14*34; u += 256) {
        int c = u / (14*34);
        int rem = u % (14*34);
        int row = rem / 34, q4 = rem % 34;
        int yy = y0 + row - 3;
        int xx = x0 - 4 + q4*4;
        ushort4 vv = make_ushort4(0, 0, 0, 0);
        if (yy >= 0 && yy < MU && xx >= 0 && xx < MU)
            vv = *(const ushort4*)(g1b + (size_t)c*NPIX + yy*MU + xx);
        *(ushort4*)&tile[c][row][q4*4] = vv;
    }
    __syncthreads();

    float accA[3][2], accB[3][2];
    #pragma unroll
    for (int co = 0; co < 3; ++co)
        #pragma unroll
        for (int dy = 0; dy < 2; ++dy) { accA[co][dy] = 0.f; accB[co][dy] = 0.f; }

    int ry = ty*2;
    #pragma unroll
    for (int c = 0; c < 3; ++c) {
        #pragma unroll
        for (int ir = 0; ir < 8; ++ir) {
            half2r P[5];
            #pragma unroll
            for (int q = 0; q < 5; ++q)
                P[q] = *(const half2r*)&tile[c][ry + ir][2*tx + 2*q];
            #pragma unroll
            for (int dy = 0; dy < 2; ++dy) {
                int i = ir - dy;
                if (i >= 0 && i <= 6) {
                    #pragma unroll
                    for (int co = 0; co < 3; ++co) {
                        const half2r* wv = wp + ((c*7 + i)*3 + co)*8;
                        accA[co][dy] = dot2f(P[0], wv[0], accA[co][dy]);
                        accA[co][dy] = dot2f(P[1], wv[1], accA[co][dy]);
                        accA[co][dy] = dot2f(P[2], wv[2], accA[co][dy]);
                        accA[co][dy] = dot2f(P[3], wv[3], accA[co][dy]);
                        accB[co][dy] = dot2f(P[1], wv[4], accB[co][dy]);
                        accB[co][dy] = dot2f(P[2], wv[5], accB[co][dy]);
                        accB[co][dy] = dot2f(P[3], wv[6], accB[co][dy]);
                        accB[co][dy] = dot2f(P[4], wv[7], accB[co][dy]);
                    }
                }
            }
        }
    }
    #pragma unroll
    for (int dy = 0; dy < 2; ++dy) {
        size_t p = (size_t)b*3*NPIX + (size_t)(y0 + ry + dy)*MU + x0 + 2*tx;
        #pragma unroll
        for (int co = 0; co < 3; ++co)
            *(__half2*)&G2[p + (size_t)co*NPIX] =
                __float22half2_rn(make_float2(accA[co][dy], accB[co][dy]));
    }
}

// ---- S = depthwise3x3(G, kernelA); stage-1 Gram partials.
//      fp32 LDS tile [7][10][72] = 20.2 KB, 2 output rows/thread,
//      butterfly split-reduction. ----
__global__ __launch_bounds__(256, 4) void reduce_kernel(
        const __half* __restrict__ r, const __half* __restrict__ G1,
        const __half* __restrict__ G2, const float* __restrict__ kA,
        float* __restrict__ partial) {
    int b = blockIdx.z;
    __shared__ float tile[7][10][72];
    __shared__ float wsum[NENT][4];
    int tx = threadIdx.x;
    int ty = threadIdx.y;
    int tid = ty*64 + tx;
    float k[9];
    #pragma unroll
    for (int i = 0; i < 9; ++i) k[i] = kA[b*9 + i];

    const __half* srcs[7] = {
        r  + (size_t)b*NPIX,
        G1 + (size_t)b*3*NPIX, G1 + (size_t)b*3*NPIX + NPIX, G1 + (size_t)b*3*NPIX + 2*NPIX,
        G2 + (size_t)b*3*NPIX, G2 + (size_t)b*3*NPIX + NPIX, G2 + (size_t)b*3*NPIX + 2*NPIX
    };

    int x0 = blockIdx.x*64;
    int ysub = blockIdx.y*8;

    #pragma unroll
    for (int c = 0; c < 7; ++c) {
        const __half* src = srcs[c];
        for (int u = tid; u < 10*18; u += 256) {
            int row = u / 18, q4 = u % 18;
            int yy = ysub + row - 1;
            int xx = x0 - 4 + q4*4;
            float4 vv = make_float4(0.f, 0.f, 0.f, 0.f);
            if (yy >= 0 && yy < MU && xx >= 0 && xx < MU)
                vv = load_h4(src + yy*MU + xx);
            *(float4*)&tile[c][row][q4*4] = vv;
        }
    }
    __syncthreads();

    float acc[64];
    #pragma unroll
    for (int e = 0; e < 64; ++e) acc[e] = 0.f;

    int ry = ty*2;
    float S_all[7][2];
    #pragma unroll
    for (int c = 0; c < 7; ++c) {
        float S0 = 0.f, S1 = 0.f;
        #pragma unroll
        for (int t = 0; t < 4; ++t) {
            float v0 = tile[c][ry + t][tx + 3];
            float v1 = tile[c][ry + t][tx + 4];
            float v2 = tile[c][ry + t][tx + 5];
            float e0 = v0*k[0] + v1*k[1] + v2*k[2];
            float e1 = v0*k[3] + v1*k[4] + v2*k[5];
            float e2 = v0*k[6] + v1*k[7] + v2*k[8];
            if (t == 0) { S0 += e0; }
            if (t == 1) { S0 += e1; S1 += e0; }
            if (t == 2) { S0 += e2; S1 += e1; }
            if (t == 3) {           S1 += e2; }
        }
        S_all[c][0] = S0; S_all[c][1] = S1;
    }
    #pragma unroll
    for (int dy = 0; dy < 2; ++dy) {
        float rv = tile[0][ry + dy + 1][tx + 4];
        int idx = 0;
        #pragma unroll
        for (int l = 0; l < 7; ++l) {
            #pragma unroll
            for (int m = l; m < 7; ++m) {
                acc[idx] += S_all[l][dy] * S_all[m][dy];
                ++idx;
            }
        }
        #pragma unroll
        for (int l = 0; l < 7; ++l) acc[28 + l] += S_all[l][dy] * rv;
    }

    #pragma unroll
    for (int step = 0; step < 6; ++step) {
        const int mask = 1 << step;
        const int nh = 32 >> step;
        bool hi = (tx & mask) != 0;
        #pragma unroll
        for (int i = 0; i < nh; ++i) {
            float send = hi ? acc[i] : acc[i + nh];
            float got = __shfl_xor(send, mask);
            acc[i] = (hi ? acc[i + nh] : acc[i]) + got;
        }
    }
    int ent = ((tx&1)<<5) | ((tx&2)<<3) | ((tx&4)<<1)
            | ((tx&8)>>1) | ((tx&16)>>3) | ((tx&32)>>5);
    if (ent < NENT) wsum[ent][ty] = acc[0];
    __syncthreads();
    if (tid < NENT) {
        float s = wsum[tid][0] + wsum[tid][1] + wsum[tid][2] + wsum[tid][3];
        int blockLinear = blockIdx.y*4 + blockIdx.x;   // 0..127
        partial[((size_t)b*NENT + tid)*RBLK + blockLinear] = s;
    }
}

// ---- stage-2: sum RBLK (=128) per-block partials per (sample, entry) ----
__global__ void reduce2_kernel(const float* __restrict__ partial,
                               double* __restrict__ M, double* __restrict__ bv) {
    int b = blockIdx.x;
    int wave = threadIdx.x >> 6;
    int lane = threadIdx.x & 63;
    for (int e = wave; e < NENT; e += 4) {
        const float* p = partial + ((size_t)b*NENT + e)*RBLK;
        double s = (double)p[lane] + (double)p[lane + 64];
        #pragma unroll
        for (int off = 32; off; off >>= 1) s += __shfl_down(s, off);
        if (lane == 0) {
            if (e < 28) M[b*28 + e] = s;
            else        bv[b*7 + (e - 28)] = s;
        }
    }
}

// ---- per-sample 7x7 solve: f64, partial pivoting, ALL-STATIC indexing ----
__global__ __launch_bounds__(64, 1) void solve_kernel(
        const double* __restrict__ M, const double* __restrict__ bv,
        float* __restrict__ K, int B) {
    int b = blockIdx.x*64 + threadIdx.x;
    if (b >= B) return;
    double A[7][8];
    int idx = 0;
    #pragma unroll
    for (int l = 0; l < 7; ++l)
        #pragma unroll
        for (int m = l; m < 7; ++m) {
            double v = M[b*28 + idx];
            A[l][m] = v;
            A[m][l] = v;
            ++idx;
        }
    #pragma unroll
    for (int l = 0; l < 7; ++l) A[l][7] = bv[b*7 + l];

    #pragma unroll
    for (int col = 0; col < 7; ++col) {
        int piv = col;
        double mx = fabs(A[col][col]);
        #pragma unroll
        for (int rr = 0; rr < 7; ++rr) {
            if (rr > col) {
                double a = fabs(A[rr][col]);
                if (a > mx) { mx = a; piv = rr; }
            }
        }
        #pragma unroll
        for (int rr = 0; rr < 7; ++rr) {
            if (rr > col) {
                bool c = (rr == piv);
                #pragma unroll
                for (int cc = 0; cc < 8; ++cc) {
                    double t0 = A[col][cc], t1 = A[rr][cc];
                    A[col][cc] = c ? t1 : t0;
                    A[rr][cc]  = c ? t0 : t1;
                }
            }
        }
        double d = A[col][col];
        #pragma unroll
        for (int rr = 0; rr < 7; ++rr) {
            if (rr > col) {
                double fct = A[rr][col] / d;
                #pragma unroll
                for (int cc = 0; cc < 8; ++cc) A[rr][cc] -= fct * A[col][cc];
            }
        }
    }
    double Kv[7];
    #pragma unroll
    for (int rr = 6; rr >= 0; --rr) {
        double s = A[rr][7];
        #pragma unroll
        for (int cc = 0; cc < 7; ++cc)
            if (cc > rr) s -= A[rr][cc] * Kv[cc];
        Kv[rr] = s / A[rr][rr];
    }
    #pragma unroll
    for (int l = 0; l < 7; ++l) K[b*7 + l] = (float)Kv[l];
}

// ---------------- x_new = x + K^T G (fp16 intermediates, 4 px/thread) ----
__global__ void update_kernel(const float* __restrict__ x, const __half* __restrict__ r,
                              const __half* __restrict__ G1, const __half* __restrict__ G2,
                              const float* __restrict__ K, float* __restrict__ out) {
    int b = blockIdx.z;
    int p4 = blockIdx.x*256 + threadIdx.x;
    float k0 = K[b*7+0], k1 = K[b*7+1], k2 = K[b*7+2], k3 = K[b*7+3];
    float k4 = K[b*7+4], k5 = K[b*7+5], k6 = K[b*7+6];
    size_t q  = (size_t)b*(NPIX/4) + p4;
    size_t e0 = ((size_t)b*3*NPIX) + (size_t)p4*4;
    size_t er = ((size_t)b*NPIX) + (size_t)p4*4;

    float4 xv = ((const float4*)x)[q];
    float4 rv = load_h4(r + er);
    float4 a  = load_h4(G1 + e0);
    float4 bb = load_h4(G1 + e0 + NPIX);
    float4 c  = load_h4(G1 + e0 + 2*(size_t)NPIX);
    float4 d  = load_h4(G2 + e0);
    float4 e  = load_h4(G2 + e0 + NPIX);
    float4 g  = load_h4(G2 + e0 + 2*(size_t)NPIX);
    float4 o;
    o.x = xv.x + k0*rv.x + k1*a.x + k2*bb.x + k3*c.x + k4*d.x + k5*e.x + k6*g.x;
    o.y = xv.y + k0*rv.y + k1*a.y + k2*bb.y + k3*c.y + k4*d.y + k5*e.y + k6*g.y;
    o.z = xv.z + k0*rv.z + k1*a.z + k2*bb.z + k3*c.z + k4*d.z + k5*e.z + k6*g.z;
    o.w = xv.w + k0*rv.w + k1*a.w + k2*bb.w + k3*c.w + k4*d.w + k5*e.w + k6*g.w;
    ((float4*)out)[q] = o;
}

extern "C" void kernel_launch(void* const* d_in, const int* in_sizes, int n_in,
                              void* d_out, int out_size, void* d_ws, size_t ws_size,
                              hipStream_t stream) {
    const float* x       = (const float*)d_in[0];
    const float* f       = (const float*)d_in[1];
    const float* kernelA = (const float*)d_in[2];
    const float* fc1_w1  = (const float*)d_in[3];
    const float* fc1_b1  = (const float*)d_in[4];
    const float* fc1_w2  = (const float*)d_in[5];
    const float* fc1_b2  = (const float*)d_in[6];
    const float* fc2_w1  = (const float*)d_in[7];
    const float* fc2_b1  = (const float*)d_in[8];
    const float* fc2_w2  = (const float*)d_in[9];
    const float* fc2_b2  = (const float*)d_in[10];
    float* out = (float*)d_out;

    const int B = in_sizes[2] / 9;

    // workspace: doubles, fp32, packed half2 weights, then fp16 planes.
    double*  Mws = (double*)d_ws;                    // B*28
    double*  bws = Mws + (size_t)B*28;               // B*7
    float*   Kv  = (float*)(bws + (size_t)B*7);      // B*7
    float*   partial = Kv + (size_t)B*7;             // B*NENT*RBLK
    half2r*  w1p = (half2r*)(partial + (size_t)B*NENT*RBLK);  // B*168
    half2r*  w2p = w1p + (size_t)B*168;              // B*504
    __half*  r   = (__half*)(w2p + (size_t)B*504);   // B*NPIX
    __half*  G1  = r  + (size_t)B*NPIX;              // B*3*NPIX
    __half*  G2  = G1 + (size_t)B*3*NPIX;            // B*3*NPIX

    dim3 cblk(64, 4);
    dim3 rgrd(MU/64, MU/8, B);     // reduce (4 x 32 x B)
    dim3 g1grd(MU/128, MU/16, B);  // res_g1
    dim3 g2grd(MU/128, MU/8, B);   // conv7_g2

    hipLaunchKernelGGL(mlp_kernel, dim3(B), dim3(256), 0, stream,
                       kernelA, fc1_w1, fc1_b1, fc1_w2, fc1_b2,
                       fc2_w1, fc2_b1, fc2_w2, fc2_b2, w1p, w2p);
    hipLaunchKernelGGL(res_g1_kernel, g1grd, cblk, 0, stream, x, f, kernelA, w1p, r, G1);
    hipLaunchKernelGGL(conv7_g2, g2grd, cblk, 0, stream, G1, w2p, G2);
    hipLaunchKernelGGL(reduce_kernel, rgrd, cblk, 0, stream, r, G1, G2, kernelA, partial);
    hipLaunchKernelGGL(reduce2_kernel, dim3(B), dim3(256), 0, stream, partial, Mws, bws);
    hipLaunchKernelGGL(solve_kernel, dim3((B + 63)/64), dim3(64), 0, stream, Mws, bws, Kv, B);
    hipLaunchKernelGGL(update_kernel, dim3(NPIX/1024, 1, B), dim3(256), 0, stream,
                       x, r, G1, G2, Kv, out);
}